// Round 8
// baseline (1497.891 us; speedup 1.0000x reference)
//
#include <hip/hip_runtime.h>
#include <hip/hip_bf16.h>

// Problem constants
#define B_  64
#define T_  512
#define E_  256
#define H_  512
#define G4_ 2048
#define C_  4

typedef __attribute__((ext_vector_type(4))) float  f32x4;
typedef __attribute__((ext_vector_type(8))) __bf16 bf16x8;
typedef __attribute__((ext_vector_type(8))) short  short8;   // no HIP builtin 'short8'
typedef __attribute__((ext_vector_type(4))) short  s16x4;    // HIP predefines 'short4'

union V16 { f32x4 f; bf16x8 b; short8 s; };

__device__ __forceinline__ float sigmoid_(float x) { return 1.0f / (1.0f + __expf(-x)); }
__device__ __forceinline__ float tanh_(float x)    { return 1.0f - 2.0f / (__expf(2.0f * x) + 1.0f); }

// Deterministic RNE fp32 -> bf16
__device__ __forceinline__ short f2bf(float f) {
  union { float f; unsigned u; } v; v.f = f;
  return (short)((v.u + 0x7FFFu + ((v.u >> 16) & 1u)) >> 16);
}

// --- per-access MALL-coherent ops (sc0 sc1 = bypass L1+L2, coherent point) ---
__device__ __forceinline__ void store_short_llc(void* p, unsigned v) {
  asm volatile("global_store_short %0, %1, off sc0 sc1" :: "v"(p), "v"(v) : "memory");
}
__device__ __forceinline__ void store_dword_llc(void* p, float v) {
  asm volatile("global_store_dword %0, %1, off sc0 sc1" :: "v"(p), "v"(v) : "memory");
}
// two coherent 16B loads from two addresses, one drain (staging 16 batches)
__device__ __forceinline__ void ld2_b128_llc2(const void* p0, const void* p1,
                                              f32x4& a, f32x4& b) {
  asm volatile("global_load_dwordx4 %0, %2, off sc0 sc1\n\t"
               "global_load_dwordx4 %1, %3, off sc0 sc1\n\t"
               "s_waitcnt vmcnt(0)"
               : "=&v"(a), "=&v"(b) : "v"(p0), "v"(p1) : "memory");
}

// ---------------------------------------------------------------------------
// One-time W_ih fp32 -> bf16 converter (r9 win).
// ---------------------------------------------------------------------------
__global__ __launch_bounds__(256, 1) void wih_conv(const float* __restrict__ W,
                                                   short* __restrict__ out) {
  const int i = (blockIdx.x * 256 + threadIdx.x) * 4;   // grid 512 -> 524288 elems
  f32x4 v = *(const f32x4*)(W + i);
  s16x4 s;
  s[0] = f2bf(v[0]); s[1] = f2bf(v[1]); s[2] = f2bf(v[2]); s[3] = f2bf(v[3]);
  *(s16x4*)(out + i) = s;
}

// ---------------------------------------------------------------------------
// Phase 1: xg[t][g][b][d] — r14 coalesced C-write version, SEPARATE dispatch
// (proven 145us; cross-kernel visibility via kernel-boundary flush).
// ---------------------------------------------------------------------------
union XgSmem {
  struct { int idx[B_]; short e[B_][E_ + 8]; } g;   // gather phase (34 KB)
  short o[4][64][136];                              // epilogue staging (68 KB)
};

template<bool WBF16>
__global__ __launch_bounds__(256, 2) void xg_kernel(
    const int* __restrict__ x, const float* __restrict__ emb,
    const void* __restrict__ Wv,
    __hip_bfloat16* __restrict__ xg)
{
  const int t   = blockIdx.x;
  const int tid = threadIdx.x;
  __shared__ XgSmem sm;

  if (tid < B_) sm.g.idx[tid] = x[tid * T_ + t];
  __syncthreads();
  {
    int b = tid >> 2, ch = tid & 3;
    const float* src = emb + (size_t)sm.g.idx[b] * E_ + ch * 64;
    short* dst = &sm.g.e[b][ch * 64];
#pragma unroll
    for (int i = 0; i < 16; i++) {
      f32x4 v = *(const f32x4*)(src + i * 4);
      s16x4 s;
      s[0] = f2bf(v[0]); s[1] = f2bf(v[1]); s[2] = f2bf(v[2]); s[3] = f2bf(v[3]);
      *(s16x4*)(dst + i * 4) = s;
    }
  }
  __syncthreads();

  const int wv   = tid >> 6;
  const int lane = tid & 63;
  const int ln15 = lane & 15, quad = lane >> 4;

  V16 breg[4][8];
#pragma unroll
  for (int nt = 0; nt < 4; nt++)
#pragma unroll
    for (int ks = 0; ks < 8; ks++)
      breg[nt][ks].f = *(const f32x4*)(&sm.g.e[nt * 16 + ln15][quad * 8 + ks * 32]);
  __syncthreads();   // all waves done reading s_e before s_o overwrites it

  const int gbase = wv * 512;
  const size_t base_t = (size_t)t * (G4_ * B_);

  for (int q = 0; q < 4; q++) {
#pragma unroll
    for (int m8 = 0; m8 < 8; m8++) {
      const int mt = q * 8 + m8;
      V16 areg[8];
      if constexpr (WBF16) {
        const short* arow = (const short*)Wv + (size_t)(gbase + mt * 16 + ln15) * E_ + quad * 8;
#pragma unroll
        for (int ks = 0; ks < 8; ks++)
          areg[ks].f = *(const f32x4*)(arow + ks * 32);
      } else {
        const float* arow = (const float*)Wv + (size_t)(gbase + mt * 16 + ln15) * E_ + quad * 8;
#pragma unroll
        for (int ks = 0; ks < 8; ks++) {
          f32x4 lo = *(const f32x4*)(arow + ks * 32);
          f32x4 hi = *(const f32x4*)(arow + ks * 32 + 4);
          short8 s;
          s[0] = f2bf(lo[0]); s[1] = f2bf(lo[1]); s[2] = f2bf(lo[2]); s[3] = f2bf(lo[3]);
          s[4] = f2bf(hi[0]); s[5] = f2bf(hi[1]); s[6] = f2bf(hi[2]); s[7] = f2bf(hi[3]);
          areg[ks].s = s;
        }
      }

      f32x4 acc[4];
#pragma unroll
      for (int nt = 0; nt < 4; nt++) acc[nt] = (f32x4){0.f, 0.f, 0.f, 0.f};
#pragma unroll
      for (int ks = 0; ks < 8; ks++)
#pragma unroll
        for (int nt = 0; nt < 4; nt++)
          acc[nt] = __builtin_amdgcn_mfma_f32_16x16x32_bf16(areg[ks].b, breg[nt][ks].b, acc[nt], 0, 0, 0);

      const int dl = m8 * 16 + quad * 4;
#pragma unroll
      for (int nt = 0; nt < 4; nt++) {
        const int batch = nt * 16 + ln15;
        s16x4 sv;
#pragma unroll
        for (int r = 0; r < 4; r++) sv[r] = f2bf(acc[nt][r]);
        *(s16x4*)&sm.o[wv][batch][dl] = sv;
      }
    }

    const size_t qbase = base_t + ((size_t)wv << 15) + q * 128;
    const int chunk = lane & 15;
#pragma unroll
    for (int i = 0; i < 16; i++) {
      const int row = (lane >> 4) + i * 4;
      f32x4 v = *(const f32x4*)&sm.o[wv][row][chunk * 8];
      *(f32x4*)((short*)xg + qbase + ((size_t)row << 9) + chunk * 8) = v;
    }
  }
}

// ---------------------------------------------------------------------------
// Phase 2: r10 PROTOCOL BYTE-IDENTICAL (flag poll + staged coherent b128 +
// s_pre + 4 barriers + coalesced 128B/wave short h-stores + S4 drain), at
// HALF the block population: 32 blocks = 4 batch-groups x 16 REAL batches
// (no phantom zeros in the MFMA B-operand) x 8 dim-slices. Purpose: isolate
// MALL-client contention (r19 showed RT-count is not the binder; this tests
// whether population is). Zero VGPR change; arithmetic order per output
// unchanged -> bitwise-identical results.
// ---------------------------------------------------------------------------
__global__ __launch_bounds__(512, 2) void lstm_kernel(
    const float* __restrict__ W_hh,
    const float* __restrict__ b_ih, const float* __restrict__ b_hh,
    const float* __restrict__ W_fc, const float* __restrict__ b_fc,
    const __hip_bfloat16* __restrict__ xg,
    unsigned int* flags, __hip_bfloat16* hbuf /*[2][64][512]*/, float* hT,
    float* out)
{
  const int tid  = threadIdx.x;
  const int blk  = blockIdx.x;     // 0..31
  const int g    = blk & 3;        // batch group (16 batches)
  const int pd   = blk >> 2;       // dim slice [pd*64, +64), 0..7
  const int d0   = pd * 64;
  const int wv   = tid >> 6;       // 0..7
  const int lane = tid & 63;
  const int ln15 = lane & 15, quad = lane >> 4;

  __shared__ __hip_bfloat16 s_h[16][520];   // 16 REAL batches (no phantoms)
  __shared__ float s_pre[4][16][68];        // [gate][batch][dim(+4 pad)]

  const int gate  = wv >> 1;
  const int dhalf = (wv & 1) * 32;
  V16 areg[2][16];                          // unchanged from r10
#pragma unroll
  for (int tau = 0; tau < 2; tau++) {
    const int grow = gate * 512 + d0 + dhalf + tau * 16 + ln15;
    const float* ap = W_hh + (size_t)grow * H_ + quad * 8;
#pragma unroll
    for (int ks = 0; ks < 16; ks++) {
      f32x4 lo = *(const f32x4*)(ap + ks * 32);
      f32x4 hi = *(const f32x4*)(ap + ks * 32 + 4);
      short8 s;
      s[0] = f2bf(lo[0]); s[1] = f2bf(lo[1]); s[2] = f2bf(lo[2]); s[3] = f2bf(lo[3]);
      s[4] = f2bf(hi[0]); s[5] = f2bf(hi[1]); s[6] = f2bf(hi[2]); s[7] = f2bf(hi[3]);
      areg[tau][ks].s = s;
    }
  }

  const int nb = tid >> 6;         // 0..7
  const int nd = tid & 63;         // 0..63
  const int gb = g * 16 + nb;      // first batch; second = gb + 8
  const int dg = d0 + nd;          // global h-dim
  const float bias_i = b_ih[dg]        + b_hh[dg];
  const float bias_f = b_ih[512 + dg]  + b_hh[512 + dg];
  const float bias_g = b_ih[1024 + dg] + b_hh[1024 + dg];
  const float bias_o = b_ih[1536 + dg] + b_hh[1536 + dg];
  float c0 = 0.0f, c1 = 0.0f;
  const int myflag = g * 16 + pd;  // g<4, pd<8 -> unique in [0,56)

  for (int t = 0; t < T_; t++) {
    const int cur = t & 1, nxt = cur ^ 1;

    // xg loads at loop top (hidden under poll+staging+MFMA); 2 batches
    const size_t xoff  = (size_t)t * (G4_ * B_) + ((size_t)gb << 9) + dg;
    const size_t xoff2 = xoff + (8u << 9);   // batch gb+8
    const __hip_bfloat16 xgi0 = xg[xoff];
    const __hip_bfloat16 xgf0 = xg[xoff + (1u << 15)];
    const __hip_bfloat16 xgg0 = xg[xoff + (2u << 15)];
    const __hip_bfloat16 xgo0 = xg[xoff + (3u << 15)];
    const __hip_bfloat16 xgi1 = xg[xoff2];
    const __hip_bfloat16 xgf1 = xg[xoff2 + (1u << 15)];
    const __hip_bfloat16 xgg1 = xg[xoff2 + (2u << 15)];
    const __hip_bfloat16 xgo1 = xg[xoff2 + (3u << 15)];

    if (tid < 8) {
      const unsigned* fp = flags + g * 16 + tid;
      while (__hip_atomic_load(fp, __ATOMIC_RELAXED, __HIP_MEMORY_SCOPE_AGENT) < (unsigned)t) {}
    }
    __syncthreads();   // S1: h_t visible at MALL

    {
      const short* hbase = (const short*)hbuf + (size_t)cur * (B_ * H_) + (size_t)(g * 16) * H_;
      f32x4 va, vb;
      ld2_b128_llc2(hbase + tid * 8, hbase + 4096 + tid * 8, va, vb);
      *(f32x4*)&s_h[tid >> 6][(tid & 63) * 8]       = va;   // batches 0-7
      *(f32x4*)&s_h[8 + (tid >> 6)][(tid & 63) * 8] = vb;   // batches 8-15
    }
    __syncthreads();   // S2: LDS staging complete

    f32x4 acc0 = (f32x4){0.f, 0.f, 0.f, 0.f};
    f32x4 acc1 = (f32x4){0.f, 0.f, 0.f, 0.f};
#pragma unroll
    for (int ks = 0; ks < 16; ks++) {
      V16 b0;
      b0.f = *(const f32x4*)&s_h[ln15][quad * 8 + ks * 32];
      acc0 = __builtin_amdgcn_mfma_f32_16x16x32_bf16(areg[0][ks].b, b0.b, acc0, 0, 0, 0);
      acc1 = __builtin_amdgcn_mfma_f32_16x16x32_bf16(areg[1][ks].b, b0.b, acc1, 0, 0, 0);
    }

    // all 16 ln15 rows are real batches now: no guard
    *(f32x4*)&s_pre[gate][ln15][dhalf + quad * 4]      = acc0;
    *(f32x4*)&s_pre[gate][ln15][dhalf + 16 + quad * 4] = acc1;
    __syncthreads();   // S3: preactivations complete

    {
      // batch gb
      const float pi0 = s_pre[0][nb][nd] + bias_i + __bfloat162float(xgi0);
      const float pf0 = s_pre[1][nb][nd] + bias_f + __bfloat162float(xgf0);
      const float pg0 = s_pre[2][nb][nd] + bias_g + __bfloat162float(xgg0);
      const float po0 = s_pre[3][nb][nd] + bias_o + __bfloat162float(xgo0);
      const float i0 = sigmoid_(pi0), f0 = sigmoid_(pf0);
      const float g0 = tanh_(pg0),    o0 = sigmoid_(po0);
      c0 = f0 * c0 + i0 * g0;
      const float h0 = o0 * tanh_(c0);
      // batch gb+8
      const float pi1 = s_pre[0][8 + nb][nd] + bias_i + __bfloat162float(xgi1);
      const float pf1 = s_pre[1][8 + nb][nd] + bias_f + __bfloat162float(xgf1);
      const float pg1 = s_pre[2][8 + nb][nd] + bias_g + __bfloat162float(xgg1);
      const float po1 = s_pre[3][8 + nb][nd] + bias_o + __bfloat162float(xgo1);
      const float i1 = sigmoid_(pi1), f1 = sigmoid_(pf1);
      const float g1 = tanh_(pg1),    o1 = sigmoid_(po1);
      c1 = f1 * c1 + i1 * g1;
      const float h1 = o1 * tanh_(c1);

      if (t < T_ - 1) {
        short* sb = (short*)hbuf + (size_t)nxt * (B_ * H_);
        store_short_llc(sb + (size_t)gb * H_ + dg,
                        (unsigned)(unsigned short)f2bf(h0));
        store_short_llc(sb + (size_t)(gb + 8) * H_ + dg,
                        (unsigned)(unsigned short)f2bf(h1));
      } else {
        store_dword_llc(hT + gb * H_ + dg, h0);
        store_dword_llc(hT + (gb + 8) * H_ + dg, h1);
      }
    }
    __syncthreads();   // S4: implicit vmcnt(0) drain -> h stores acked at MALL

    if (tid == 0)
      __hip_atomic_store(&flags[myflag], (unsigned)(t + 1),
                         __ATOMIC_RELAXED, __HIP_MEMORY_SCOPE_AGENT);
  }

  // Phase 3: fp32 FC by block 0 (waits on all 32 flags)
  if (blk == 0) {
    if (tid < 32)
      while (__hip_atomic_load(flags + (tid >> 3) * 16 + (tid & 7),
                               __ATOMIC_RELAXED, __HIP_MEMORY_SCOPE_AGENT) < (unsigned)T_) {}
    __builtin_amdgcn_fence(__ATOMIC_ACQUIRE, "agent");
    __syncthreads();
    for (int o = tid; o < B_ * C_; o += 512) {
      const int b = o >> 2, cl = o & 3;
      const f32x4* hr = (const f32x4*)(hT + b * H_);
      const f32x4* wr = (const f32x4*)(W_fc + cl * H_);
      float s = 0.f;
      for (int d4 = 0; d4 < H_ / 4; d4++) {
        const f32x4 hv = hr[d4];
        const f32x4 wv4 = wr[d4];
        s += hv[0] * wv4[0] + hv[1] * wv4[1] + hv[2] * wv4[2] + hv[3] * wv4[3];
      }
      s += b_fc[cl];
      out[o] = s;
    }
  }
}

// ---------------------------------------------------------------------------
// Workspace map (r10 layout):
//   [0, 1024)            : flags (group g's 8 slice-flags at words [g*16,+8))
//   [4096, 135168)       : hbuf[2][64][512] bf16 (zeroed = h0)
//   [135168, 266240)     : hT[64][512] fp32
//   [524288, 134742016)  : xg[T][4][B][512] bf16 (128 MiB)
//   [134742016, 135790592): W_ih bf16 table (1 MiB) — only if ws_size allows
// ---------------------------------------------------------------------------
extern "C" void kernel_launch(void* const* d_in, const int* in_sizes, int n_in,
                              void* d_out, int out_size, void* d_ws, size_t ws_size,
                              hipStream_t stream) {
  const int*   x    = (const int*)d_in[0];
  const float* emb  = (const float*)d_in[1];
  const float* W_ih = (const float*)d_in[2];
  const float* W_hh = (const float*)d_in[3];
  const float* b_ih = (const float*)d_in[4];
  const float* b_hh = (const float*)d_in[5];
  const float* W_fc = (const float*)d_in[6];
  const float* b_fc = (const float*)d_in[7];
  float* out = (float*)d_out;

  char* ws = (char*)d_ws;
  const size_t XG_OFF  = 524288;
  const size_t XG_END  = XG_OFF + (size_t)T_ * G4_ * B_ * 2;   // 134,742,016
  const size_t NEEDED2 = XG_END + (size_t)G4_ * E_ * 2;        // +1 MiB bf16 W_ih
  if (ws_size < XG_END) return;

  unsigned int*   flags = (unsigned int*)ws;
  __hip_bfloat16* hbuf  = (__hip_bfloat16*)(ws + 4096);
  float*          hT    = (float*)(ws + 135168);
  __hip_bfloat16* xg    = (__hip_bfloat16*)(ws + XG_OFF);
  short*          wih16 = (short*)(ws + XG_END);

  (void)hipMemsetAsync(ws, 0, 135168, stream);

  if (ws_size >= NEEDED2) {
    wih_conv<<<512, 256, 0, stream>>>(W_ih, wih16);
    xg_kernel<true><<<T_, 256, 0, stream>>>(x, emb, wih16, xg);
  } else {
    xg_kernel<false><<<T_, 256, 0, stream>>>(x, emb, W_ih, xg);
  }
  lstm_kernel<<<32, 512, 0, stream>>>(W_hh, b_ih, b_hh, W_fc, b_fc, xg,
                                      flags, hbuf, hT, out);
}

// Round 9
// 1433.010 us; speedup vs baseline: 1.0453x; 1.0453x over previous
//
#include <hip/hip_runtime.h>
#include <hip/hip_bf16.h>

// Problem constants
#define B_  64
#define T_  512
#define E_  256
#define H_  512
#define G4_ 2048
#define C_  4

typedef __attribute__((ext_vector_type(4))) float  f32x4;
typedef __attribute__((ext_vector_type(8))) __bf16 bf16x8;
typedef __attribute__((ext_vector_type(8))) short  short8;   // no HIP builtin 'short8'
typedef __attribute__((ext_vector_type(4))) short  s16x4;    // HIP predefines 'short4'

union V16 { f32x4 f; bf16x8 b; short8 s; };

__device__ __forceinline__ float sigmoid_(float x) { return 1.0f / (1.0f + __expf(-x)); }
__device__ __forceinline__ float tanh_(float x)    { return 1.0f - 2.0f / (__expf(2.0f * x) + 1.0f); }

// Deterministic RNE fp32 -> bf16
__device__ __forceinline__ short f2bf(float f) {
  union { float f; unsigned u; } v; v.f = f;
  return (short)((v.u + 0x7FFFu + ((v.u >> 16) & 1u)) >> 16);
}

// --- per-access MALL-coherent ops (sc0 sc1 = bypass L1+L2, coherent point) ---
__device__ __forceinline__ void store_short_llc(void* p, unsigned v) {
  asm volatile("global_store_short %0, %1, off sc0 sc1" :: "v"(p), "v"(v) : "memory");
}
__device__ __forceinline__ void store_dword_llc(void* p, float v) {
  asm volatile("global_store_dword %0, %1, off sc0 sc1" :: "v"(p), "v"(v) : "memory");
}
// one coherent 16B load + drain (staging)
__device__ __forceinline__ f32x4 ld_b128_llc(const void* p) {
  f32x4 v;
  asm volatile("global_load_dwordx4 %0, %1, off sc0 sc1\n\ts_waitcnt vmcnt(0)"
               : "=&v"(v) : "v"(p) : "memory");
  return v;
}

// ---------------------------------------------------------------------------
// Single persistent kernel. lstm geometry/protocol = r10 BYTE-IDENTICAL
// (64 blocks = 8 batch-groups x 8 dim-slices; flag poll + staged coherent
// b128 + s_pre + 4 barriers + coalesced 128B/wave short h-stores + S4
// drain; bracketing rounds r19/r21 proved this is the protocol floor).
// NEW (r22): the input-side GEMM (xg = e @ W_ih^T) is computed INLINE.
//  - aregI[2][8]: this block's W_ih slice (same gate rows, K=256) in regs.
//  - s_e dbuf: 8 embedding rows (bf16) staged one step ahead (x[b][t+1] is
//    statically known -> no dependence, plain cached loads).
//  - per step: 16 ih-MFMAs run BEFORE the h-poll (fills poll slack; no
//    recurrence dependence), hh-MFMAs continue the same fp32 accumulator.
// Deletes xg_kernel + wih_conv + 128MiB xg tensor -> ~145us of serial
// pre-phase becomes ~0. The ih part is no longer rounded through bf16
// storage (strictly less rounding than r0).
// ---------------------------------------------------------------------------
__global__ __launch_bounds__(512, 1) void lstm_kernel(
    const int* __restrict__ x, const float* __restrict__ emb,
    const float* __restrict__ W_ih, const float* __restrict__ W_hh,
    const float* __restrict__ b_ih, const float* __restrict__ b_hh,
    const float* __restrict__ W_fc, const float* __restrict__ b_fc,
    unsigned int* flags, __hip_bfloat16* hbuf /*[2][64][512]*/, float* hT,
    float* out)
{
  const int tid  = threadIdx.x;
  const int blk  = blockIdx.x;
  const int g    = blk & 7;        // batch group (8 batches)
  const int pd   = blk >> 3;       // dim slice [pd*64, +64)
  const int d0   = pd * 64;
  const int wv   = tid >> 6;       // 0..7
  const int lane = tid & 63;
  const int ln15 = lane & 15, quad = lane >> 4;

  __shared__ __hip_bfloat16 s_h[16][520];   // rows 0-7: batches; 8-15: zeros
  __shared__ float s_pre[4][8][68];         // [gate][batch][dim(+4 pad)]
  __shared__ __hip_bfloat16 s_e[2][16][264]; // dbuf embeddings; rows 8-15 zero

  const int gate  = wv >> 1;
  const int dhalf = (wv & 1) * 32;
  const int grow  = gate * 512 + d0 + dhalf;

  // A-regs: W_hh slice (r0 verbatim) + W_ih slice (same rows, K=256)
  V16 aregH[2][16];
  V16 aregI[2][8];
#pragma unroll
  for (int tau = 0; tau < 2; tau++) {
    const int r = grow + tau * 16 + ln15;
    {
      const float* ap = W_hh + (size_t)r * H_ + quad * 8;
#pragma unroll
      for (int ks = 0; ks < 16; ks++) {
        f32x4 lo = *(const f32x4*)(ap + ks * 32);
        f32x4 hi = *(const f32x4*)(ap + ks * 32 + 4);
        short8 s;
        s[0] = f2bf(lo[0]); s[1] = f2bf(lo[1]); s[2] = f2bf(lo[2]); s[3] = f2bf(lo[3]);
        s[4] = f2bf(hi[0]); s[5] = f2bf(hi[1]); s[6] = f2bf(hi[2]); s[7] = f2bf(hi[3]);
        aregH[tau][ks].s = s;
      }
    }
    {
      const float* ap = W_ih + (size_t)r * E_ + quad * 8;
#pragma unroll
      for (int ks = 0; ks < 8; ks++) {
        f32x4 lo = *(const f32x4*)(ap + ks * 32);
        f32x4 hi = *(const f32x4*)(ap + ks * 32 + 4);
        short8 s;
        s[0] = f2bf(lo[0]); s[1] = f2bf(lo[1]); s[2] = f2bf(lo[2]); s[3] = f2bf(lo[3]);
        s[4] = f2bf(hi[0]); s[5] = f2bf(hi[1]); s[6] = f2bf(hi[2]); s[7] = f2bf(hi[3]);
        aregI[tau][ks].s = s;
      }
    }
  }

  const int nb = tid >> 6;         // 0..7  (== wv)
  const int nd = tid & 63;         // 0..63
  const int gb = g * 8 + nb;       // global batch
  const int dg = d0 + nd;          // global h-dim
  const float bias_i = b_ih[dg]        + b_hh[dg];
  const float bias_f = b_ih[512 + dg]  + b_hh[512 + dg];
  const float bias_g = b_ih[1024 + dg] + b_hh[1024 + dg];
  const float bias_o = b_ih[1536 + dg] + b_hh[1536 + dg];
  float c = 0.0f;
  const int myflag = g * 16 + pd;

  // zero phantom rows: s_h rows 8-15 (r0) + s_e rows 8-15 of both buffers
  *(f32x4*)&s_h[8 + wv][lane * 8] = (f32x4){0.f, 0.f, 0.f, 0.f};
  {
    const int buf = tid >> 8, row = 8 + ((tid >> 5) & 7), col = (tid & 31) * 8;
    short8 z = (short8){0,0,0,0,0,0,0,0};
    *(short8*)&s_e[buf][row][col] = z;
  }
  // stage e(0) into buffer 0: thread covers batch nb, dims nd*4..+4
  {
    const int idx0 = x[gb * T_ + 0];
    f32x4 v = *(const f32x4*)(emb + (size_t)idx0 * E_ + nd * 4);
    s16x4 sv;
    sv[0] = f2bf(v[0]); sv[1] = f2bf(v[1]); sv[2] = f2bf(v[2]); sv[3] = f2bf(v[3]);
    *(s16x4*)&s_e[0][nb][nd * 4] = sv;
  }
  __syncthreads();   // prologue staging visible

  for (int t = 0; t < T_; t++) {
    const int cur = t & 1, nxt = cur ^ 1;

    // 1. ih-MFMAs for step t (no recurrence dependence; fills poll slack)
    f32x4 acc0 = (f32x4){0.f, 0.f, 0.f, 0.f};
    f32x4 acc1 = (f32x4){0.f, 0.f, 0.f, 0.f};
#pragma unroll
    for (int ks = 0; ks < 8; ks++) {
      V16 b0;
      b0.f = *(const f32x4*)&s_e[cur][ln15][quad * 8 + ks * 32];
      acc0 = __builtin_amdgcn_mfma_f32_16x16x32_bf16(aregI[0][ks].b, b0.b, acc0, 0, 0, 0);
      acc1 = __builtin_amdgcn_mfma_f32_16x16x32_bf16(aregI[1][ks].b, b0.b, acc1, 0, 0, 0);
    }

    // 2. issue e(t+1) loads (plain cached; emb is read-only)
    f32x4 ev;
    if (t + 1 < T_) {
      const int idx1 = x[gb * T_ + t + 1];
      ev = *(const f32x4*)(emb + (size_t)idx1 * E_ + nd * 4);
    }

    // 3. poll peers' h(t) flags (r10 verbatim)
    if (tid < 8) {
      const unsigned* fp = flags + g * 16 + tid;
      while (__hip_atomic_load(fp, __ATOMIC_RELAXED, __HIP_MEMORY_SCOPE_AGENT) < (unsigned)t) {}
    }
    __syncthreads();   // S1: h_t visible at MALL

    // 4. stage h(t) (coherent, coalesced)
    {
      const short* hbase = (const short*)hbuf + (size_t)cur * (B_ * H_) + (size_t)(g * 8) * H_;
      f32x4 va = ld_b128_llc(hbase + tid * 8);
      *(f32x4*)&s_h[tid >> 6][(tid & 63) * 8] = va;
    }
    __syncthreads();   // S2: LDS staging complete

    // 5. hh-MFMAs continue the same accumulator
#pragma unroll
    for (int ks = 0; ks < 16; ks++) {
      V16 b0;
      b0.f = *(const f32x4*)&s_h[ln15][quad * 8 + ks * 32];
      acc0 = __builtin_amdgcn_mfma_f32_16x16x32_bf16(aregH[0][ks].b, b0.b, acc0, 0, 0, 0);
      acc1 = __builtin_amdgcn_mfma_f32_16x16x32_bf16(aregH[1][ks].b, b0.b, acc1, 0, 0, 0);
    }

    if (ln15 < 8) {
      *(f32x4*)&s_pre[gate][ln15][dhalf + quad * 4]      = acc0;
      *(f32x4*)&s_pre[gate][ln15][dhalf + 16 + quad * 4] = acc1;
    }
    __syncthreads();   // S3: preactivations complete

    // 6. gate math (pre already includes ih+hh; just add bias)
    {
      const float pi = s_pre[0][nb][nd] + bias_i;
      const float pf = s_pre[1][nb][nd] + bias_f;
      const float pg = s_pre[2][nb][nd] + bias_g;
      const float po = s_pre[3][nb][nd] + bias_o;
      const float i_ = sigmoid_(pi), f_ = sigmoid_(pf);
      const float g_ = tanh_(pg),    o_ = sigmoid_(po);
      c = f_ * c + i_ * g_;
      const float h = o_ * tanh_(c);
      if (t < T_ - 1) {
        store_short_llc((short*)hbuf + (size_t)nxt * (B_ * H_) + (size_t)gb * H_ + dg,
                        (unsigned)(unsigned short)f2bf(h));
      } else {
        store_dword_llc(hT + gb * H_ + dg, h);
      }
    }

    // 7. stage e(t+1) into the other buffer (covered by S4)
    if (t + 1 < T_) {
      s16x4 sv;
      sv[0] = f2bf(ev[0]); sv[1] = f2bf(ev[1]); sv[2] = f2bf(ev[2]); sv[3] = f2bf(ev[3]);
      *(s16x4*)&s_e[nxt][nb][nd * 4] = sv;
    }
    __syncthreads();   // S4: vmcnt(0) drain -> h stores acked; s_e(t+1) visible

    if (tid == 0)
      __hip_atomic_store(&flags[myflag], (unsigned)(t + 1),
                         __ATOMIC_RELAXED, __HIP_MEMORY_SCOPE_AGENT);
  }

  // Phase 3: fp32 FC by block 0 (r0 verbatim)
  if (blk == 0) {
    if (tid < 64)
      while (__hip_atomic_load(flags + (tid >> 3) * 16 + (tid & 7),
                               __ATOMIC_RELAXED, __HIP_MEMORY_SCOPE_AGENT) < (unsigned)T_) {}
    __builtin_amdgcn_fence(__ATOMIC_ACQUIRE, "agent");
    __syncthreads();
    for (int o = tid; o < B_ * C_; o += 512) {
      const int b = o >> 2, cl = o & 3;
      const f32x4* hr = (const f32x4*)(hT + b * H_);
      const f32x4* wr = (const f32x4*)(W_fc + cl * H_);
      float s = 0.f;
      for (int d4 = 0; d4 < H_ / 4; d4++) {
        const f32x4 hv = hr[d4];
        const f32x4 wv4 = wr[d4];
        s += hv[0] * wv4[0] + hv[1] * wv4[1] + hv[2] * wv4[2] + hv[3] * wv4[3];
      }
      s += b_fc[cl];
      out[o] = s;
    }
  }
}

// ---------------------------------------------------------------------------
// Workspace map (xg tensor GONE — only control + h state needed):
//   [0, 1024)            : flags[256] (group g's 8 flags at words [g*16,+8))
//   [4096, 135168)       : hbuf[2][64][512] bf16 (zeroed = h0)
//   [135168, 266240)     : hT[64][512] fp32
// ---------------------------------------------------------------------------
extern "C" void kernel_launch(void* const* d_in, const int* in_sizes, int n_in,
                              void* d_out, int out_size, void* d_ws, size_t ws_size,
                              hipStream_t stream) {
  const int*   x    = (const int*)d_in[0];
  const float* emb  = (const float*)d_in[1];
  const float* W_ih = (const float*)d_in[2];
  const float* W_hh = (const float*)d_in[3];
  const float* b_ih = (const float*)d_in[4];
  const float* b_hh = (const float*)d_in[5];
  const float* W_fc = (const float*)d_in[6];
  const float* b_fc = (const float*)d_in[7];
  float* out = (float*)d_out;

  char* ws = (char*)d_ws;
  if (ws_size < 266240) return;

  unsigned int*   flags = (unsigned int*)ws;
  __hip_bfloat16* hbuf  = (__hip_bfloat16*)(ws + 4096);
  float*          hT    = (float*)(ws + 135168);

  (void)hipMemsetAsync(ws, 0, 135168, stream);

  lstm_kernel<<<64, 512, 0, stream>>>(x, emb, W_ih, W_hh, b_ih, b_hh,
                                      W_fc, b_fc, flags, hbuf, hT, out);
}